// Round 5
// baseline (59.891 us; speedup 1.0000x reference)
//
#include <hip/hip_runtime.h>
#include <math.h>

namespace {

constexpr int kB = 4;
constexpr int kS = 4;
constexpr int kM = 1024;
constexpr int kN = 8192;
constexpr int kBS = kB * kS;
constexpr float kBig2 = 1e20f;  // sqrt(1e20) = 1e10 == reference BIG

// ---- workspace layout (4-byte words) ----
constexpr int OFF_D1 = 0;                        // kBS*kM min-d2 bits
constexpr int OFF_DM = OFF_D1 + kBS * kM;        // kBS*kN min-d2 bits
constexpr int MINS_WORDS = kBS * kM + kBS * kN;  // 147456
constexpr int OFF_C4 = MINS_WORDS;               // float4[kBS*kN] gt {x,y,z,|g|^2}
constexpr int OFF_P4 = OFF_C4 + 4 * kBS * kN;    // float4[kBS*kM] pred {x,y,z,|p|^2}
constexpr int OFF_CUR = OFF_P4 + 4 * kBS * kM;   // 16 scatter cursors (memset 0)
constexpr int OFF_DONE1 = OFF_CUR + kBS;         // 16 per-bs dist-done counters
constexpr int OFF_DONE2 = OFF_DONE1 + kBS;       // 1 bs-reduce-done counter
constexpr int OFF_CHAM = OFF_DONE2 + 1;          // 16 chamfer bits

constexpr int INIT_BLOCKS = MINS_WORDS / 1024;   // 144 (uint4 stores)
constexpr int P4_BLOCKS = kBS * kM / 256;        // 64
constexpr int SCAT_BLOCKS = kB * kN / 256;       // 128

constexpr int NSPL1 = 16;                        // K1: gt split, tiles of 128
constexpr int K1_TILE = 128;
constexpr int K1_BLOCKS = kBS * NSPL1;           // 256
constexpr int GSPL = 2;                          // K2: gt chunks of 1024
constexpr int MSPL = 8;                          // K2: pred tiles of 128
constexpr int K2_BLOCKS = kBS * GSPL * MSPL;     // 256
constexpr unsigned DIST_PER_BS = NSPL1 + GSPL * MSPL;  // 32

// merged prep: init min-buffers to 0xFF (uint-min identity), zero done
// counters, build pred float4 {x,y,z,|p|^2}, scatter gt into buckets.
__global__ __launch_bounds__(256) void kprep2(const float* __restrict__ ret,
                                              const float4* __restrict__ gt,
                                              unsigned int* __restrict__ ws) {
  const int blk = blockIdx.x, tid = threadIdx.x;
  if (blk < INIT_BLOCKS) {
    ((uint4*)ws)[blk * 256 + tid] = make_uint4(~0u, ~0u, ~0u, ~0u);
    if (blk == 0 && tid < kBS + 1) ws[OFF_DONE1 + tid] = 0u;  // done1[16]+done2
    return;
  }
  if (blk < INIT_BLOCKS + P4_BLOCKS) {
    const int gi = (blk - INIT_BLOCKS) * 256 + tid;
    const float x = ret[gi * 3], y = ret[gi * 3 + 1], z = ret[gi * 3 + 2];
    ((float4*)(ws + OFF_P4))[gi] = make_float4(x, y, z, fmaf(x, x, fmaf(y, y, z * z)));
    return;
  }
  // scatter: cursors pre-zeroed by hipMemsetAsync; wave-aggregated allocs.
  const int idx = (blk - INIT_BLOCKS - P4_BLOCKS) * 256 + tid;
  const int b = idx >> 13;
  const int lane = tid & 63;
  const float4 q = gt[idx];
  const int s = (int)q.w;
  int* cur = (int*)ws + OFF_CUR;
  int pos = 0;
  for (int ss = 0; ss < kS; ++ss) {
    unsigned long long m = __ballot(s == ss);
    if (m != 0ull) {
      const int leader = __ffsll((unsigned long long)m) - 1;
      int base = 0;
      if (lane == leader) base = atomicAdd(&cur[b * kS + ss], (int)__popcll(m));
      base = __shfl(base, leader);
      if (s == ss) pos = base + (int)__popcll(m & ((1ull << lane) - 1ull));
    }
  }
  const float gn = fmaf(q.x, q.x, fmaf(q.y, q.y, q.z * q.z));
  ((float4*)(ws + OFF_C4))[(b * kS + s) * kN + pos] = make_float4(q.x, q.y, q.z, gn);
}

// dist (dot-expansion, 3 FMA + 1 min per pair) with fused per-bs reduction:
// the 32nd dist block to finish a bs reduces it; the 16th bs-reducer writes out.
__global__ __launch_bounds__(256) void kdist2(unsigned int* __restrict__ ws,
                                              float* __restrict__ out) {
  const int tid = threadIdx.x;
  __shared__ float4 tile[K1_TILE];
  __shared__ int amLast;
  __shared__ float r1[4], r2[4];
  const int* cur = (const int*)ws + OFF_CUR;
  const float4* c4 = (const float4*)(ws + OFF_C4);
  const float4* p4 = (const float4*)(ws + OFF_P4);

  int bs, cnt;
  if (blockIdx.x < K1_BLOCKS) {
    const int t = blockIdx.x & (NSPL1 - 1);
    bs = blockIdx.x >> 4;
    cnt = cur[bs];
    const float4 P0 = p4[bs * kM + tid];
    const float4 P1 = p4[bs * kM + tid + 256];
    const float4 P2 = p4[bs * kM + tid + 512];
    const float4 P3 = p4[bs * kM + tid + 768];
    const float ax0 = -2.f * P0.x, ay0 = -2.f * P0.y, az0 = -2.f * P0.z;
    const float ax1 = -2.f * P1.x, ay1 = -2.f * P1.y, az1 = -2.f * P1.z;
    const float ax2 = -2.f * P2.x, ay2 = -2.f * P2.y, az2 = -2.f * P2.z;
    const float ax3 = -2.f * P3.x, ay3 = -2.f * P3.y, az3 = -2.f * P3.z;
    float b0 = kBig2, b1 = kBig2, b2 = kBig2, b3 = kBig2;
    for (int start = t * K1_TILE; start < cnt; start += NSPL1 * K1_TILE) {
      __syncthreads();
      if (tid < K1_TILE) {
        const int j = start + tid;
        tile[tid] = (j < cnt) ? c4[bs * kN + j] : make_float4(0.f, 0.f, 0.f, kBig2);
      }
      __syncthreads();
#pragma unroll 8
      for (int j = 0; j < K1_TILE; ++j) {
        const float4 g = tile[j];  // wave-uniform -> LDS broadcast
        b0 = fminf(b0, fmaf(ax0, g.x, fmaf(ay0, g.y, fmaf(az0, g.z, g.w))));
        b1 = fminf(b1, fmaf(ax1, g.x, fmaf(ay1, g.y, fmaf(az1, g.z, g.w))));
        b2 = fminf(b2, fmaf(ax2, g.x, fmaf(ay2, g.y, fmaf(az2, g.z, g.w))));
        b3 = fminf(b3, fmaf(ax3, g.x, fmaf(ay3, g.y, fmaf(az3, g.z, g.w))));
      }
    }
    atomicMin(&ws[OFF_D1 + bs * kM + tid],       __float_as_uint(fmaxf(b0 + P0.w, 0.f)));
    atomicMin(&ws[OFF_D1 + bs * kM + tid + 256], __float_as_uint(fmaxf(b1 + P1.w, 0.f)));
    atomicMin(&ws[OFF_D1 + bs * kM + tid + 512], __float_as_uint(fmaxf(b2 + P2.w, 0.f)));
    atomicMin(&ws[OFF_D1 + bs * kM + tid + 768], __float_as_uint(fmaxf(b3 + P3.w, 0.f)));
  } else {
    int r = blockIdx.x - K1_BLOCKS;
    const int ms = r & (MSPL - 1); r >>= 3;
    const int gs = r & (GSPL - 1); r >>= 1;
    bs = r;
    cnt = cur[bs];
    if (tid < K1_TILE) tile[tid] = p4[bs * kM + ms * K1_TILE + tid];
    __syncthreads();
    for (int base = gs * 1024; base < cnt; base += GSPL * 1024) {
      const int l0 = base + tid, l1 = l0 + 256, l2 = l0 + 512, l3 = l0 + 768;
      const bool v0 = l0 < cnt, v1 = l1 < cnt, v2 = l2 < cnt, v3 = l3 < cnt;
      const float4 G0 = v0 ? c4[bs * kN + l0] : make_float4(0.f, 0.f, 0.f, 0.f);
      const float4 G1 = v1 ? c4[bs * kN + l1] : make_float4(0.f, 0.f, 0.f, 0.f);
      const float4 G2 = v2 ? c4[bs * kN + l2] : make_float4(0.f, 0.f, 0.f, 0.f);
      const float4 G3 = v3 ? c4[bs * kN + l3] : make_float4(0.f, 0.f, 0.f, 0.f);
      const float ax0 = -2.f * G0.x, ay0 = -2.f * G0.y, az0 = -2.f * G0.z;
      const float ax1 = -2.f * G1.x, ay1 = -2.f * G1.y, az1 = -2.f * G1.z;
      const float ax2 = -2.f * G2.x, ay2 = -2.f * G2.y, az2 = -2.f * G2.z;
      const float ax3 = -2.f * G3.x, ay3 = -2.f * G3.y, az3 = -2.f * G3.z;
      float b0 = kBig2, b1 = kBig2, b2 = kBig2, b3 = kBig2;
#pragma unroll 8
      for (int mm = 0; mm < K1_TILE; ++mm) {
        const float4 p = tile[mm];  // wave-uniform broadcast
        b0 = fminf(b0, fmaf(ax0, p.x, fmaf(ay0, p.y, fmaf(az0, p.z, p.w))));
        b1 = fminf(b1, fmaf(ax1, p.x, fmaf(ay1, p.y, fmaf(az1, p.z, p.w))));
        b2 = fminf(b2, fmaf(ax2, p.x, fmaf(ay2, p.y, fmaf(az2, p.z, p.w))));
        b3 = fminf(b3, fmaf(ax3, p.x, fmaf(ay3, p.y, fmaf(az3, p.z, p.w))));
      }
      if (v0) atomicMin(&ws[OFF_DM + bs * kN + l0], __float_as_uint(fmaxf(b0 + G0.w, 0.f)));
      if (v1) atomicMin(&ws[OFF_DM + bs * kN + l1], __float_as_uint(fmaxf(b1 + G1.w, 0.f)));
      if (v2) atomicMin(&ws[OFF_DM + bs * kN + l2], __float_as_uint(fmaxf(b2 + G2.w, 0.f)));
      if (v3) atomicMin(&ws[OFF_DM + bs * kN + l3], __float_as_uint(fmaxf(b3 + G3.w, 0.f)));
    }
  }

  // ---- fused per-bs reduction: last of the 32 dist blocks for this bs ----
  __syncthreads();  // drains all this block's atomicMins (vmcnt 0 at barrier)
  if (tid == 0) {
    __threadfence();
    const unsigned old = atomicAdd(&ws[OFF_DONE1 + bs], 1u);
    amLast = (old == DIST_PER_BS - 1) ? 1 : 0;
  }
  __syncthreads();
  if (!amLast) return;

  float s1 = 0.f;
  for (int m = tid; m < kM; m += 256) {
    const unsigned u = __hip_atomic_load(&ws[OFF_D1 + bs * kM + m],
                                         __ATOMIC_RELAXED, __HIP_MEMORY_SCOPE_AGENT);
    s1 += sqrtf(fmaxf(__uint_as_float(u), 1e-12f));
  }
  float s2 = 0.f;
  for (int i = tid; i < cnt; i += 256) {
    const unsigned u = __hip_atomic_load(&ws[OFF_DM + bs * kN + i],
                                         __ATOMIC_RELAXED, __HIP_MEMORY_SCOPE_AGENT);
    s2 += sqrtf(fmaxf(__uint_as_float(u), 1e-12f));
  }
  for (int o = 32; o > 0; o >>= 1) {
    s1 += __shfl_down(s1, o);
    s2 += __shfl_down(s2, o);
  }
  const int lane = tid & 63, wid = tid >> 6;
  if (lane == 0) { r1[wid] = s1; r2[wid] = s2; }
  __syncthreads();
  if (tid != 0) return;

  const float a1 = r1[0] + r1[1] + r1[2] + r1[3];
  const float a2 = r2[0] + r2[1] + r2[2] + r2[3];
  const float cham = cnt > 0 ? 0.5f * (a1 / (float)kM + a2 / (float)max(cnt, 1)) : 0.f;
  __hip_atomic_store(&ws[OFF_CHAM + bs], __float_as_uint(cham),
                     __ATOMIC_RELEASE, __HIP_MEMORY_SCOPE_AGENT);
  const unsigned old2 = __hip_atomic_fetch_add(&ws[OFF_DONE2], 1u,
                                               __ATOMIC_ACQ_REL, __HIP_MEMORY_SCOPE_AGENT);
  if (old2 != kBS - 1) return;

  // final combine: this thread is the 16th (last) bs-reducer.
  float acc = 0.f;
  for (int b = 0; b < kB; ++b) {
    float sum = 0.f;
    int pres = 0;
#pragma unroll
    for (int s = 0; s < kS; ++s) {
      const unsigned cu = __hip_atomic_load(&ws[OFF_CHAM + b * kS + s],
                                            __ATOMIC_ACQUIRE, __HIP_MEMORY_SCOPE_AGENT);
      sum += __uint_as_float(cu);
      pres += cur[b * kS + s] > 0 ? 1 : 0;
    }
    acc += sum / (float)max(pres, 1);
  }
  out[0] = acc / (float)kB;
}

}  // namespace

extern "C" void kernel_launch(void* const* d_in, const int* in_sizes, int n_in,
                              void* d_out, int out_size, void* d_ws, size_t ws_size,
                              hipStream_t stream) {
  const float* ret = (const float*)d_in[0];    // (B, S*M*3) f32 == (BS, M, 3)
  const float4* gt = (const float4*)d_in[1];   // (B, N, 4) f32
  unsigned int* ws = (unsigned int*)d_ws;

  // zero the 16 scatter cursors (64 B) — graph-capture-legal async memset.
  hipMemsetAsync((char*)d_ws + (size_t)OFF_CUR * 4, 0, kBS * 4, stream);
  kprep2<<<INIT_BLOCKS + P4_BLOCKS + SCAT_BLOCKS, 256, 0, stream>>>(ret, gt, ws);
  kdist2<<<K1_BLOCKS + K2_BLOCKS, 256, 0, stream>>>(ws, (float*)d_out);
}

// Round 6
// 33.491 us; speedup vs baseline: 1.7883x; 1.7883x over previous
//
#include <hip/hip_runtime.h>
#include <math.h>

namespace {

constexpr int kB = 4;
constexpr int kS = 4;
constexpr int kM = 1024;
constexpr int kN = 8192;
constexpr int kBS = kB * kS;
constexpr float kBig2 = 1e20f;  // sqrt(1e20) = 1e10 == reference BIG

// ---- workspace layout (4-byte words) ----
constexpr int OFF_D1 = 0;                        // kBS*kM min-d2 bits
constexpr int OFF_DM = OFF_D1 + kBS * kM;        // kBS*kN min-d2 bits
constexpr int MINS_WORDS = kBS * kM + kBS * kN;  // 147456
constexpr int OFF_C4 = MINS_WORDS;               // float4[kBS*kN] gt {x,y,z,|g|^2}
constexpr int OFF_P4 = OFF_C4 + 4 * kBS * kN;    // float4[kBS*kM] pred {x,y,z,|p|^2}
constexpr int OFF_CUR = OFF_P4 + 4 * kBS * kM;   // 16 scatter cursors (absolute)

constexpr int INIT_BLOCKS = MINS_WORDS / 1024;   // 144 (uint4 stores)
constexpr int P4_BLOCKS = kBS * kM / 256;        // 64
constexpr int SCAT_BLOCKS = kB * kN / 256;       // 128

constexpr int NSPL1 = 16;                        // K1: gt split, tiles of 128
constexpr int K1_TILE = 128;
constexpr int K1_BLOCKS = kBS * NSPL1;           // 256
constexpr int GSPL = 2;                          // K2: gt chunks of 1024
constexpr int MSPL = 8;                          // K2: pred tiles of 128
constexpr int K2_BLOCKS = kBS * GSPL * MSPL;     // 256

// init min-buffers to 0xFF (uint-min identity) via uint4, build pred float4
// {x,y,z,|p|^2}, set cursors to absolute bucket bases, zero out[0].
__global__ __launch_bounds__(256) void kprep(const float* __restrict__ ret,
                                             unsigned int* __restrict__ ws,
                                             float* __restrict__ out) {
  const int blk = blockIdx.x, tid = threadIdx.x;
  if (blk < INIT_BLOCKS) {
    ((uint4*)ws)[blk * 256 + tid] = make_uint4(~0u, ~0u, ~0u, ~0u);
    return;
  }
  if (blk < INIT_BLOCKS + P4_BLOCKS) {
    const int gi = (blk - INIT_BLOCKS) * 256 + tid;
    const float x = ret[gi * 3], y = ret[gi * 3 + 1], z = ret[gi * 3 + 2];
    ((float4*)(ws + OFF_P4))[gi] = make_float4(x, y, z, fmaf(x, x, fmaf(y, y, z * z)));
    return;
  }
  if (tid < kBS) ((int*)ws)[OFF_CUR + tid] = tid * kN;  // absolute bases
  if (tid == kBS) out[0] = 0.f;
}

// scatter gt into fixed per-(b,s) regions. Block-aggregated allocation:
// one global atomicAdd per (block,label) instead of one per wave per label.
__global__ __launch_bounds__(256) void kscatter(const float4* __restrict__ gt,
                                                unsigned int* __restrict__ ws) {
  const int tid = threadIdx.x;
  const int idx = blockIdx.x * 256 + tid;  // single b per block (8192 % 256 == 0)
  const int b = idx >> 13;
  const int wave = tid >> 6, lane = tid & 63;
  const float4 q = gt[idx];
  const int s = (int)q.w;
  __shared__ int wcnt[4][kS];   // per-wave label counts
  __shared__ int bbase[kS];     // per-block absolute base per label
  int rank = 0;
#pragma unroll
  for (int ss = 0; ss < kS; ++ss) {
    const unsigned long long m = __ballot(s == ss);
    if (lane == 0) wcnt[wave][ss] = (int)__popcll(m);
    if (s == ss) rank = (int)__popcll(m & ((1ull << lane) - 1ull));
  }
  __syncthreads();
  if (tid < kS) {
    const int tot = wcnt[0][tid] + wcnt[1][tid] + wcnt[2][tid] + wcnt[3][tid];
    bbase[tid] = atomicAdd((int*)ws + OFF_CUR + b * kS + tid, tot);
  }
  __syncthreads();
  int pos = bbase[s] + rank;
#pragma unroll
  for (int w = 0; w < 4; ++w)
    if (w < wave) pos += wcnt[w][s];
  const float gn = fmaf(q.x, q.x, fmaf(q.y, q.y, q.z * q.z));
  ((float4*)(ws + OFF_C4))[pos] = make_float4(q.x, q.y, q.z, gn);
}

// merged distance kernel, dot-expansion form: per pair 3 FMA + 1 min.
// K1 blocks: per (b,s,m) min over bucket. K2 blocks: per gt point min over M.
__global__ __launch_bounds__(256) void kdist(unsigned int* __restrict__ ws) {
  const int tid = threadIdx.x;
  __shared__ float4 tile[K1_TILE];
  const int* cur = (const int*)ws + OFF_CUR;
  const float4* c4 = (const float4*)(ws + OFF_C4);
  const float4* p4 = (const float4*)(ws + OFF_P4);

  if (blockIdx.x < K1_BLOCKS) {
    const int t = blockIdx.x & (NSPL1 - 1);
    const int bs = blockIdx.x >> 4;
    const int cnt = cur[bs] - bs * kN;
    const float4 P0 = p4[bs * kM + tid];
    const float4 P1 = p4[bs * kM + tid + 256];
    const float4 P2 = p4[bs * kM + tid + 512];
    const float4 P3 = p4[bs * kM + tid + 768];
    const float ax0 = -2.f * P0.x, ay0 = -2.f * P0.y, az0 = -2.f * P0.z;
    const float ax1 = -2.f * P1.x, ay1 = -2.f * P1.y, az1 = -2.f * P1.z;
    const float ax2 = -2.f * P2.x, ay2 = -2.f * P2.y, az2 = -2.f * P2.z;
    const float ax3 = -2.f * P3.x, ay3 = -2.f * P3.y, az3 = -2.f * P3.z;
    float b0 = kBig2, b1 = kBig2, b2 = kBig2, b3 = kBig2;
    for (int start = t * K1_TILE; start < cnt; start += NSPL1 * K1_TILE) {
      __syncthreads();
      if (tid < K1_TILE) {
        const int j = start + tid;
        tile[tid] = (j < cnt) ? c4[bs * kN + j] : make_float4(0.f, 0.f, 0.f, kBig2);
      }
      __syncthreads();
#pragma unroll 8
      for (int j = 0; j < K1_TILE; ++j) {
        const float4 g = tile[j];  // wave-uniform -> LDS broadcast
        b0 = fminf(b0, fmaf(ax0, g.x, fmaf(ay0, g.y, fmaf(az0, g.z, g.w))));
        b1 = fminf(b1, fmaf(ax1, g.x, fmaf(ay1, g.y, fmaf(az1, g.z, g.w))));
        b2 = fminf(b2, fmaf(ax2, g.x, fmaf(ay2, g.y, fmaf(az2, g.z, g.w))));
        b3 = fminf(b3, fmaf(ax3, g.x, fmaf(ay3, g.y, fmaf(az3, g.z, g.w))));
      }
    }
    // +|p|^2 outside the min; clamp: negative bits would lose the uint-min.
    atomicMin(&ws[OFF_D1 + bs * kM + tid],       __float_as_uint(fmaxf(b0 + P0.w, 0.f)));
    atomicMin(&ws[OFF_D1 + bs * kM + tid + 256], __float_as_uint(fmaxf(b1 + P1.w, 0.f)));
    atomicMin(&ws[OFF_D1 + bs * kM + tid + 512], __float_as_uint(fmaxf(b2 + P2.w, 0.f)));
    atomicMin(&ws[OFF_D1 + bs * kM + tid + 768], __float_as_uint(fmaxf(b3 + P3.w, 0.f)));
  } else {
    int r = blockIdx.x - K1_BLOCKS;
    const int ms = r & (MSPL - 1); r >>= 3;
    const int gs = r & (GSPL - 1); r >>= 1;
    const int bs = r;
    const int cnt = cur[bs] - bs * kN;
    if (tid < K1_TILE) tile[tid] = p4[bs * kM + ms * K1_TILE + tid];
    __syncthreads();
    for (int base = gs * 1024; base < cnt; base += GSPL * 1024) {
      const int l0 = base + tid, l1 = l0 + 256, l2 = l0 + 512, l3 = l0 + 768;
      const bool v0 = l0 < cnt, v1 = l1 < cnt, v2 = l2 < cnt, v3 = l3 < cnt;
      const float4 G0 = v0 ? c4[bs * kN + l0] : make_float4(0.f, 0.f, 0.f, 0.f);
      const float4 G1 = v1 ? c4[bs * kN + l1] : make_float4(0.f, 0.f, 0.f, 0.f);
      const float4 G2 = v2 ? c4[bs * kN + l2] : make_float4(0.f, 0.f, 0.f, 0.f);
      const float4 G3 = v3 ? c4[bs * kN + l3] : make_float4(0.f, 0.f, 0.f, 0.f);
      const float ax0 = -2.f * G0.x, ay0 = -2.f * G0.y, az0 = -2.f * G0.z;
      const float ax1 = -2.f * G1.x, ay1 = -2.f * G1.y, az1 = -2.f * G1.z;
      const float ax2 = -2.f * G2.x, ay2 = -2.f * G2.y, az2 = -2.f * G2.z;
      const float ax3 = -2.f * G3.x, ay3 = -2.f * G3.y, az3 = -2.f * G3.z;
      float b0 = kBig2, b1 = kBig2, b2 = kBig2, b3 = kBig2;
#pragma unroll 8
      for (int mm = 0; mm < K1_TILE; ++mm) {
        const float4 p = tile[mm];  // wave-uniform broadcast
        b0 = fminf(b0, fmaf(ax0, p.x, fmaf(ay0, p.y, fmaf(az0, p.z, p.w))));
        b1 = fminf(b1, fmaf(ax1, p.x, fmaf(ay1, p.y, fmaf(az1, p.z, p.w))));
        b2 = fminf(b2, fmaf(ax2, p.x, fmaf(ay2, p.y, fmaf(az2, p.z, p.w))));
        b3 = fminf(b3, fmaf(ax3, p.x, fmaf(ay3, p.y, fmaf(az3, p.z, p.w))));
      }
      if (v0) atomicMin(&ws[OFF_DM + bs * kN + l0], __float_as_uint(fmaxf(b0 + G0.w, 0.f)));
      if (v1) atomicMin(&ws[OFF_DM + bs * kN + l1], __float_as_uint(fmaxf(b1 + G1.w, 0.f)));
      if (v2) atomicMin(&ws[OFF_DM + bs * kN + l2], __float_as_uint(fmaxf(b2 + G2.w, 0.f)));
      if (v3) atomicMin(&ws[OFF_DM + bs * kN + l3], __float_as_uint(fmaxf(b3 + G3.w, 0.f)));
    }
  }
}

// fused epilogue: one block per (b,s); pres_b from cursors; atomicAdd into out.
__global__ __launch_bounds__(256) void krf(const unsigned int* __restrict__ ws,
                                           float* __restrict__ out) {
  const int tid = threadIdx.x, lane = tid & 63, wid = tid >> 6;
  const int bs = blockIdx.x, b = bs >> 2;
  const int* cur = (const int*)ws + OFF_CUR;
  const int cnt = cur[bs] - bs * kN;
  float s1 = 0.f;
  for (int m = tid; m < kM; m += 256)
    s1 += sqrtf(fmaxf(__uint_as_float(ws[OFF_D1 + bs * kM + m]), 1e-12f));
  float s2 = 0.f;
  for (int i = tid; i < cnt; i += 256)
    s2 += sqrtf(fmaxf(__uint_as_float(ws[OFF_DM + bs * kN + i]), 1e-12f));
  for (int o = 32; o > 0; o >>= 1) {
    s1 += __shfl_down(s1, o);
    s2 += __shfl_down(s2, o);
  }
  __shared__ float r1[4], r2[4];
  if (lane == 0) { r1[wid] = s1; r2[wid] = s2; }
  __syncthreads();
  if (tid == 0) {
    const float a1 = r1[0] + r1[1] + r1[2] + r1[3];
    const float a2 = r2[0] + r2[1] + r2[2] + r2[3];
    int pres = 0;
    for (int s = 0; s < kS; ++s) pres += (cur[b * kS + s] - (b * kS + s) * kN) > 0 ? 1 : 0;
    const float cham = cnt > 0 ? 0.5f * (a1 / (float)kM + a2 / (float)max(cnt, 1)) : 0.f;
    atomicAdd(out, cham / (float)(kB * max(pres, 1)));
  }
}

}  // namespace

extern "C" void kernel_launch(void* const* d_in, const int* in_sizes, int n_in,
                              void* d_out, int out_size, void* d_ws, size_t ws_size,
                              hipStream_t stream) {
  const float* ret = (const float*)d_in[0];    // (B, S*M*3) f32 == (BS, M, 3)
  const float4* gt = (const float4*)d_in[1];   // (B, N, 4) f32
  unsigned int* ws = (unsigned int*)d_ws;
  float* out = (float*)d_out;

  kprep<<<INIT_BLOCKS + P4_BLOCKS + 1, 256, 0, stream>>>(ret, ws, out);
  kscatter<<<SCAT_BLOCKS, 256, 0, stream>>>(gt, ws);
  kdist<<<K1_BLOCKS + K2_BLOCKS, 256, 0, stream>>>(ws);
  krf<<<kBS, 256, 0, stream>>>(ws, out);
}